// Round 4
// baseline (7646.562 us; speedup 1.0000x reference)
//
#include <hip/hip_runtime.h>
#include <hip/hip_bf16.h>
#include <stdint.h>

typedef __hip_bfloat16 bf16;
typedef __attribute__((ext_vector_type(8))) short s16x8;
typedef __attribute__((ext_vector_type(4))) float f32x4;

#define MFMA_BF16 __builtin_amdgcn_mfma_f32_16x16x32_bf16

// T=128, B=128, H=1024, I=2048. M = T*B = 16384. Gate order i,f,g,o.
// ALL d_in / d_out storage is FLOAT32 (values bf16-quantized by harness).
//
// Workspace layout:
//   WHH6b  bf16 [4096][1024] @ 0           ( 8,388,608 B)
//   WHH10b bf16 [4096][1024] @  8,388,608  ( 8,388,608 B)
//   OUT7b  bf16 [16384][1024] @ 16,777,216 (33,554,432 B)  h1 history (bf16)
//   ZERO   bf16 [131072]     @ 50,331,648  (   262,144 B)
//   H2A    bf16 [131072]     @ 50,593,792  (   262,144 B)
//   H2B    bf16 [131072]     @ 50,855,936  (   262,144 B)
//   C1     f32  [131072]     @ 51,118,080  (   524,288 B)
//   C2     f32  [131072]     @ 51,642,368  (   524,288 B)
//   Xc     f32  [TC*128][4096] @ 52,166,656 (TC*2,097,152 B; TC adaptive)

__device__ __forceinline__ float sigmoidf_(float x) {
  return 1.0f / (1.0f + __expf(-x));
}
__device__ __forceinline__ float tanhf_(float x) {
  return 2.0f / (1.0f + __expf(-2.0f * x)) - 1.0f;
}

__device__ __forceinline__ s16x8 cvt8(const float* __restrict__ p) {
  s16x8 r;
#pragma unroll
  for (int i = 0; i < 8; i++) {
    bf16 h = __float2bfloat16(p[i]);   // exact: values are bf16-grid
    r[i] = *(const short*)&h;
  }
  return r;
}

// f32 -> bf16 bulk convert; each thread does 8 elements.
__global__ __launch_bounds__(256)
void cvt_k(const float* __restrict__ src, bf16* __restrict__ dst) {
  const size_t i = (size_t)(blockIdx.x * 256 + threadIdx.x) * 8;
  *(s16x8*)(dst + i) = cvt8(src + i);
}

// X[m][n] = sum_k concat(A0,A1)[row_base+m][k] * W[n][k] + b0[n] + b1[n]
// A0: [16384][1024] bf16 (a0_bf=1) or f32 (a0_bf=0); A1: [16384][1024] f32.
// W: [4096][2048] f32; X: [TC*128][4096] f32. grid = (32, TC), block 256.
__global__ __launch_bounds__(256)
void gemm_xp(const void* __restrict__ A0, int a0_bf,
             const float* __restrict__ A1f, const float* __restrict__ Wf,
             const float* __restrict__ b0, const float* __restrict__ b1,
             float* __restrict__ X, int row_base)
{
  __shared__ short As[128][32];
  __shared__ short Bs[128][32];
  const int tid = threadIdx.x;
  const int wave = tid >> 6, lane = tid & 63;
  const int lr = lane & 15, lq = lane >> 4;
  const int wm = wave >> 1, wn = wave & 1;
  const int lrow0 = blockIdx.y * 128;          // local row in chunk
  const int grow0 = row_base + lrow0;          // global row in [0,16384)
  const int col0 = blockIdx.x * 128;

  f32x4 acc[4][4];
  const f32x4 z = {0.f, 0.f, 0.f, 0.f};
  for (int i = 0; i < 4; i++)
    for (int j = 0; j < 4; j++) acc[i][j] = z;

  const int sr = tid >> 2;            // 0..63
  const int skk = (tid & 3) * 8;      // 0,8,16,24

  for (int k0 = 0; k0 < 2048; k0 += 32) {
    if (k0 < 1024) {
      if (a0_bf) {
        const bf16* Ab = (const bf16*)A0;
        *(s16x8*)&As[sr][skk]      = *(const s16x8*)(Ab + (size_t)(grow0 + sr) * 1024 + k0 + skk);
        *(s16x8*)&As[sr + 64][skk] = *(const s16x8*)(Ab + (size_t)(grow0 + sr + 64) * 1024 + k0 + skk);
      } else {
        const float* Af = (const float*)A0;
        *(s16x8*)&As[sr][skk]      = cvt8(Af + (size_t)(grow0 + sr) * 1024 + k0 + skk);
        *(s16x8*)&As[sr + 64][skk] = cvt8(Af + (size_t)(grow0 + sr + 64) * 1024 + k0 + skk);
      }
    } else {
      const int ac = k0 - 1024;
      *(s16x8*)&As[sr][skk]      = cvt8(A1f + (size_t)(grow0 + sr) * 1024 + ac + skk);
      *(s16x8*)&As[sr + 64][skk] = cvt8(A1f + (size_t)(grow0 + sr + 64) * 1024 + ac + skk);
    }
    *(s16x8*)&Bs[sr][skk]      = cvt8(Wf + (size_t)(col0 + sr) * 2048 + k0 + skk);
    *(s16x8*)&Bs[sr + 64][skk] = cvt8(Wf + (size_t)(col0 + sr + 64) * 2048 + k0 + skk);
    __syncthreads();
    s16x8 bfrag[4];
    for (int nt = 0; nt < 4; nt++)
      bfrag[nt] = *(const s16x8*)&Bs[wn * 64 + nt * 16 + lr][lq * 8];
    for (int mt = 0; mt < 4; mt++) {
      s16x8 a = *(const s16x8*)&As[wm * 64 + mt * 16 + lr][lq * 8];
      for (int nt = 0; nt < 4; nt++)
        acc[mt][nt] = MFMA_BF16(a, bfrag[nt], acc[mt][nt], 0, 0, 0);
    }
    __syncthreads();
  }

  for (int mt = 0; mt < 4; mt++) {
    const int mbase = lrow0 + wm * 64 + mt * 16 + lq * 4;   // local row
    for (int nt = 0; nt < 4; nt++) {
      const int n = col0 + wn * 64 + nt * 16 + lr;
      const float bias = b0[n] + b1[n];
      for (int r = 0; r < 4; r++)
        X[(size_t)(mbase + r) * 4096 + n] = acc[mt][nt][r] + bias;
    }
  }
}

// One LSTM timestep, fused gates GEMM + pointwise.
// grid = 128 blocks: bid&63 = j-tile (16 cols), bid>>6 = batch half (64 rows).
// Each block covers gate columns {j0..j0+15} at offsets {0,1024,2048,3072}, K=1024.
// Outputs out_a (out11[t]) / out_b (out14[t] left half) are FLOAT32.
__global__ __launch_bounds__(256)
void lstm_step(const bf16* __restrict__ h_prev, const bf16* __restrict__ w_hh,
               const float* __restrict__ xp_t, float* __restrict__ c,
               bf16* __restrict__ h_next, const bf16* __restrict__ add_in,
               float* __restrict__ out_a, float* __restrict__ out_b, int do_out)
{
  const int tid = threadIdx.x;
  const int wave = tid >> 6, lane = tid & 63;
  const int lr = lane & 15, lq = lane >> 4;
  const int jb = blockIdx.x & 63, mb = blockIdx.x >> 6;
  const int j0 = jb * 16;
  const int rowb = mb * 64 + wave * 16;

  f32x4 acc[4];
  const f32x4 z = {0.f, 0.f, 0.f, 0.f};
  acc[0] = z; acc[1] = z; acc[2] = z; acc[3] = z;

  const bf16* ap  = h_prev + (size_t)(rowb + lr) * 1024 + lq * 8;
  const bf16* bp0 = w_hh + (size_t)(       j0 + lr) * 1024 + lq * 8;
  const bf16* bp1 = w_hh + (size_t)(1024 + j0 + lr) * 1024 + lq * 8;
  const bf16* bp2 = w_hh + (size_t)(2048 + j0 + lr) * 1024 + lq * 8;
  const bf16* bp3 = w_hh + (size_t)(3072 + j0 + lr) * 1024 + lq * 8;

  for (int k0 = 0; k0 < 1024; k0 += 32) {
    s16x8 a = *(const s16x8*)(ap + k0);
    acc[0] = MFMA_BF16(a, *(const s16x8*)(bp0 + k0), acc[0], 0, 0, 0);
    acc[1] = MFMA_BF16(a, *(const s16x8*)(bp1 + k0), acc[1], 0, 0, 0);
    acc[2] = MFMA_BF16(a, *(const s16x8*)(bp2 + k0), acc[2], 0, 0, 0);
    acc[3] = MFMA_BF16(a, *(const s16x8*)(bp3 + k0), acc[3], 0, 0, 0);
  }

  const int j = j0 + lr;
  for (int r = 0; r < 4; r++) {
    const int b = rowb + lq * 4 + r;
    const float gi = acc[0][r] + xp_t[b * 4096 + j];
    const float gf = acc[1][r] + xp_t[b * 4096 + 1024 + j];
    const float gg = acc[2][r] + xp_t[b * 4096 + 2048 + j];
    const float go = acc[3][r] + xp_t[b * 4096 + 3072 + j];
    const float i_ = sigmoidf_(gi);
    const float f_ = sigmoidf_(gf);
    const float g_ = tanhf_(gg);
    const float o_ = sigmoidf_(go);
    const int idx = b * 1024 + j;
    const float cn = f_ * c[idx] + i_ * g_;
    c[idx] = cn;
    const float hn = o_ * tanhf_(cn);
    h_next[idx] = __float2bfloat16(hn);
    if (do_out) {
      const float ov = hn + __bfloat162float(add_in[idx]);   // out11 = h2 + out7
      out_a[idx] = ov;                  // o11[t] (f32)
      out_b[b * 2048 + j] = ov;         // o14[t][:, 0:1024] (f32)
    }
  }
}

// out1 = input4 (f32 copy); out14[:, :, 1024:2048] = input4
__global__ __launch_bounds__(256)
void finalize_k(const float4* __restrict__ in4, float4* __restrict__ out1,
                float* __restrict__ out14)
{
  const int ci = blockIdx.x * 256 + threadIdx.x;   // 4,194,304 chunks of 4 f32
  float4 v = in4[ci];
  out1[ci] = v;
  const int flat = ci * 4;
  const int row = flat >> 10, j = flat & 1023;
  *(float4*)&out14[(size_t)row * 2048 + 1024 + j] = v;
}

extern "C" void kernel_launch(void* const* d_in, const int* in_sizes, int n_in,
                              void* d_out, int out_size, void* d_ws, size_t ws_size,
                              hipStream_t stream)
{
  const float* input4 = (const float*)d_in[0];
  const float* input0 = (const float*)d_in[1];
  const float* w_ih6  = (const float*)d_in[2];
  const float* w_hh6  = (const float*)d_in[3];
  const float* b_ih6  = (const float*)d_in[4];
  const float* b_hh6  = (const float*)d_in[5];
  const float* w_ih10 = (const float*)d_in[6];
  const float* w_hh10 = (const float*)d_in[7];
  const float* b_ih10 = (const float*)d_in[8];
  const float* b_hh10 = (const float*)d_in[9];

  char* ws = (char*)d_ws;
  bf16* WHH6b  = (bf16*)(ws);                       //  8,388,608 B
  bf16* WHH10b = (bf16*)(ws + 8388608ull);          //  8,388,608 B
  bf16* OUT7b  = (bf16*)(ws + 16777216ull);         // 33,554,432 B
  bf16* ZERO   = (bf16*)(ws + 50331648ull);         //    262,144 B
  bf16* H2A    = (bf16*)(ws + 50593792ull);         //    262,144 B
  bf16* H2B    = (bf16*)(ws + 50855936ull);         //    262,144 B
  float* C1    = (float*)(ws + 51118080ull);        //    524,288 B
  float* C2    = (float*)(ws + 51642368ull);        //    524,288 B
  float* Xc    = (float*)(ws + 52166656ull);        // TC * 2,097,152 B

  // Adaptive chunk size: TC timesteps of xp (f32 [TC*128][4096]) must fit.
  const size_t small_bytes = 52166656ull;
  size_t avail = (ws_size > small_bytes) ? (ws_size - small_bytes) : 0;
  int TC = 16;
  while (TC > 1 && (size_t)TC * 2097152ull > avail) TC >>= 1;
  const int NCH = 128 / TC;

  hipMemsetAsync(ZERO, 0, 262144, stream);
  hipMemsetAsync(C1, 0, 524288, stream);
  hipMemsetAsync(C2, 0, 524288, stream);

  // Convert recurrent weights to bf16 (lossless: values are bf16-grid).
  cvt_k<<<2048, 256, 0, stream>>>(w_hh6, WHH6b);
  cvt_k<<<2048, 256, 0, stream>>>(w_hh10, WHH10b);

  float* o1  = (float*)d_out;
  float* o11 = o1 + 16777216;   // [16384][1024] f32
  float* o14 = o1 + 33554432;   // [16384][2048] f32

  const dim3 ggrid(32, TC);

  // ---- Layer 1: x = [input0 | input4] (both f32), h history -> OUT7b ----
  for (int ch = 0; ch < NCH; ++ch) {
    gemm_xp<<<ggrid, 256, 0, stream>>>(input0, 0, input4, w_ih6, b_ih6, b_hh6,
                                       Xc, ch * TC * 128);
    for (int tt = 0; tt < TC; ++tt) {
      const int t = ch * TC + tt;
      const bf16* hp = (t == 0) ? ZERO : (OUT7b + (size_t)(t - 1) * 131072);
      lstm_step<<<128, 256, 0, stream>>>(hp, WHH6b,
                                         Xc + (size_t)tt * 524288, C1,
                                         OUT7b + (size_t)t * 131072,
                                         nullptr, nullptr, nullptr, 0);
    }
  }

  // ---- Layer 2: x = [out7(bf16) | input4(f32)] ----
  for (int ch = 0; ch < NCH; ++ch) {
    gemm_xp<<<ggrid, 256, 0, stream>>>(OUT7b, 1, input4, w_ih10, b_ih10, b_hh10,
                                       Xc, ch * TC * 128);
    for (int tt = 0; tt < TC; ++tt) {
      const int t = ch * TC + tt;
      const bf16* hp = (t == 0) ? ZERO : ((t & 1) ? H2A : H2B);
      bf16* hn = (t & 1) ? H2B : H2A;
      lstm_step<<<128, 256, 0, stream>>>(hp, WHH10b,
                                         Xc + (size_t)tt * 524288, C2,
                                         hn,
                                         OUT7b + (size_t)t * 131072,   // out7[t]
                                         o11 + (size_t)t * 131072,     // out11[t] f32
                                         o14 + (size_t)t * 262144, 1);
    }
  }

  finalize_k<<<16384, 256, 0, stream>>>((const float4*)input4, (float4*)d_out, o14);
}